// Round 7
// baseline (324.735 us; speedup 1.0000x reference)
//
#include <hip/hip_runtime.h>

#define S 256
#define D 256
#define DFF 1024

// ---------------- wave helpers ----------------
__device__ __forceinline__ float wave_sum(float v) {
#pragma unroll
    for (int o = 32; o; o >>= 1) v += __shfl_xor(v, o, 64);
    return v;
}
__device__ __forceinline__ float wave_max(float v) {
#pragma unroll
    for (int o = 32; o; o >>= 1) v = fmaxf(v, __shfl_xor(v, o, 64));
    return v;
}

// ---------- K1: embedding + positional encoding (grid 512, block 256) ----------
__global__ __launch_bounds__(256) void k_embed(
    const int* __restrict__ x, const float* __restrict__ mask,
    const int* __restrict__ use_pos, const float* __restrict__ pos_enc,
    const float* __restrict__ emb_W, const float* __restrict__ emb_b,
    float* __restrict__ h)
{
    __shared__ float red[4];
    int r = blockIdx.x, d = threadIdx.x;
    int b = r >> 8, s = r & 255;
    float mv = (d <= s) ? (1.0f - mask[b * S + d]) : 0.0f;
    float w = wave_sum(mv);
    if (!(threadIdx.x & 63)) red[threadIdx.x >> 6] = w;
    __syncthreads();
    float cum = red[0] + red[1] + red[2] + red[3];
    int idx = (int)(cum + 0.5f);
    int xv = x[r];
    float acc = emb_b[d];
#pragma unroll
    for (int k = 0; k < 16; k++)
        if ((xv >> k) & 1) acc += emb_W[k * D + d];
    acc *= 16.0f;
    if (use_pos[0]) acc += pos_enc[idx * D + d];
    h[r * D + d] = acc;
}

// ---------- K2: qkv = h @ wW + wb   (row-block GEMM, grid (128,4), block 256) ----------
// block: 4 rows x 64 cols, K=256 split 4 ways (wave kq = tid>>6, lane cl = tid&63)
__global__ __launch_bounds__(256) void k_qkv(
    const float* __restrict__ h, const float* __restrict__ wW, const float* __restrict__ wb,
    float* __restrict__ qkv)
{
    __shared__ float red[4][4][64];
    int r0 = blockIdx.x * 4, c0 = blockIdx.y * 64;
    int kq = threadIdx.x >> 6, cl = threadIdx.x & 63;
    int c = c0 + cl, k0 = kq * 64;
    float a0 = 0.f, a1 = 0.f, a2 = 0.f, a3 = 0.f;
#pragma unroll 4
    for (int kk = 0; kk < 64; kk += 4) {
        int k = k0 + kk;
        float4 h0 = *(const float4*)&h[(r0 + 0) * D + k];
        float4 h1 = *(const float4*)&h[(r0 + 1) * D + k];
        float4 h2 = *(const float4*)&h[(r0 + 2) * D + k];
        float4 h3 = *(const float4*)&h[(r0 + 3) * D + k];
        float w0 = wW[(k + 0) * D + c], w1 = wW[(k + 1) * D + c];
        float w2 = wW[(k + 2) * D + c], w3 = wW[(k + 3) * D + c];
        a0 = fmaf(h0.x, w0, a0); a0 = fmaf(h0.y, w1, a0); a0 = fmaf(h0.z, w2, a0); a0 = fmaf(h0.w, w3, a0);
        a1 = fmaf(h1.x, w0, a1); a1 = fmaf(h1.y, w1, a1); a1 = fmaf(h1.z, w2, a1); a1 = fmaf(h1.w, w3, a1);
        a2 = fmaf(h2.x, w0, a2); a2 = fmaf(h2.y, w1, a2); a2 = fmaf(h2.z, w2, a2); a2 = fmaf(h2.w, w3, a2);
        a3 = fmaf(h3.x, w0, a3); a3 = fmaf(h3.y, w1, a3); a3 = fmaf(h3.z, w2, a3); a3 = fmaf(h3.w, w3, a3);
    }
    red[kq][0][cl] = a0; red[kq][1][cl] = a1; red[kq][2][cl] = a2; red[kq][3][cl] = a3;
    __syncthreads();
    int r = threadIdx.x >> 6;
    float s = red[0][r][cl] + red[1][r][cl] + red[2][r][cl] + red[3][r][cl];
    qkv[(r0 + r) * D + c] = s + wb[c];
}

// ---------- K3: qa = qkv@W1a + b1 ; qbT = (qkv@W1b)^T   (grid (128,8), block 256) ----------
__global__ __launch_bounds__(256) void k_qab(
    const float* __restrict__ qkv, const float* __restrict__ nnW1, const float* __restrict__ nnb1,
    float* __restrict__ qa, float* __restrict__ qbT)
{
    __shared__ float red[4][4][64];
    int r0 = blockIdx.x * 4;
    int ct = blockIdx.y;
    int isB = ct >> 2;
    int c0 = (ct & 3) * 64;
    const float* W = nnW1 + isB * D * D;
    int kq = threadIdx.x >> 6, cl = threadIdx.x & 63;
    int c = c0 + cl, k0 = kq * 64;
    float a0 = 0.f, a1 = 0.f, a2 = 0.f, a3 = 0.f;
#pragma unroll 4
    for (int kk = 0; kk < 64; kk += 4) {
        int k = k0 + kk;
        float4 h0 = *(const float4*)&qkv[(r0 + 0) * D + k];
        float4 h1 = *(const float4*)&qkv[(r0 + 1) * D + k];
        float4 h2 = *(const float4*)&qkv[(r0 + 2) * D + k];
        float4 h3 = *(const float4*)&qkv[(r0 + 3) * D + k];
        float w0 = W[(k + 0) * D + c], w1 = W[(k + 1) * D + c];
        float w2 = W[(k + 2) * D + c], w3 = W[(k + 3) * D + c];
        a0 = fmaf(h0.x, w0, a0); a0 = fmaf(h0.y, w1, a0); a0 = fmaf(h0.z, w2, a0); a0 = fmaf(h0.w, w3, a0);
        a1 = fmaf(h1.x, w0, a1); a1 = fmaf(h1.y, w1, a1); a1 = fmaf(h1.z, w2, a1); a1 = fmaf(h1.w, w3, a1);
        a2 = fmaf(h2.x, w0, a2); a2 = fmaf(h2.y, w1, a2); a2 = fmaf(h2.z, w2, a2); a2 = fmaf(h2.w, w3, a2);
        a3 = fmaf(h3.x, w0, a3); a3 = fmaf(h3.y, w1, a3); a3 = fmaf(h3.z, w2, a3); a3 = fmaf(h3.w, w3, a3);
    }
    red[kq][0][cl] = a0; red[kq][1][cl] = a1; red[kq][2][cl] = a2; red[kq][3][cl] = a3;
    __syncthreads();
    int r = threadIdx.x >> 6;
    float s = red[0][r][cl] + red[1][r][cl] + red[2][r][cl] + red[3][r][cl];
    int row = r0 + r;
    if (!isB) {
        qa[row * D + c] = s + nnb1[c];
    } else {
        int b = row >> 8, j = row & 255;
        qbT[b * (S * D) + c * S + j] = s;
    }
}

// ---------- K4: g tile + transposed copy   (grid (128,4), block 256) ----------
// g[b,i,j] = sum_h relu(qa[i,h] + qb[j,h]) * w2[h]
__global__ __launch_bounds__(256) void k_g(
    const float* __restrict__ qa, const float* __restrict__ qbT,
    const float* __restrict__ w2, float* __restrict__ g, float* __restrict__ gT)
{
    __shared__ float red[4][4][64];
    int ri0 = blockIdx.x * 4;           // global i-row (batch folded)
    int b = ri0 >> 8;
    int j0 = blockIdx.y * 64;
    int kq = threadIdx.x >> 6, cl = threadIdx.x & 63;
    int k0 = kq * 64;
    const float* qbTb = qbT + b * (S * D);
    float a0 = 0.f, a1 = 0.f, a2 = 0.f, a3 = 0.f;
#pragma unroll 2
    for (int hh = 0; hh < 64; hh += 4) {
        int hgl = k0 + hh;
        float4 q0 = *(const float4*)&qa[(ri0 + 0) * D + hgl];
        float4 q1 = *(const float4*)&qa[(ri0 + 1) * D + hgl];
        float4 q2 = *(const float4*)&qa[(ri0 + 2) * D + hgl];
        float4 q3 = *(const float4*)&qa[(ri0 + 3) * D + hgl];
        float4 wv = *(const float4*)&w2[hgl];
        float b0 = qbTb[(hgl + 0) * S + j0 + cl];
        float b1 = qbTb[(hgl + 1) * S + j0 + cl];
        float b2 = qbTb[(hgl + 2) * S + j0 + cl];
        float b3 = qbTb[(hgl + 3) * S + j0 + cl];
        a0 = fmaf(fmaxf(q0.x + b0, 0.f), wv.x, a0); a1 = fmaf(fmaxf(q1.x + b0, 0.f), wv.x, a1);
        a2 = fmaf(fmaxf(q2.x + b0, 0.f), wv.x, a2); a3 = fmaf(fmaxf(q3.x + b0, 0.f), wv.x, a3);
        a0 = fmaf(fmaxf(q0.y + b1, 0.f), wv.y, a0); a1 = fmaf(fmaxf(q1.y + b1, 0.f), wv.y, a1);
        a2 = fmaf(fmaxf(q2.y + b1, 0.f), wv.y, a2); a3 = fmaf(fmaxf(q3.y + b1, 0.f), wv.y, a3);
        a0 = fmaf(fmaxf(q0.z + b2, 0.f), wv.z, a0); a1 = fmaf(fmaxf(q1.z + b2, 0.f), wv.z, a1);
        a2 = fmaf(fmaxf(q2.z + b2, 0.f), wv.z, a2); a3 = fmaf(fmaxf(q3.z + b2, 0.f), wv.z, a3);
        a0 = fmaf(fmaxf(q0.w + b3, 0.f), wv.w, a0); a1 = fmaf(fmaxf(q1.w + b3, 0.f), wv.w, a1);
        a2 = fmaf(fmaxf(q2.w + b3, 0.f), wv.w, a2); a3 = fmaf(fmaxf(q3.w + b3, 0.f), wv.w, a3);
    }
    red[kq][0][cl] = a0; red[kq][1][cl] = a1; red[kq][2][cl] = a2; red[kq][3][cl] = a3;
    __syncthreads();
    int r = threadIdx.x >> 6;
    float s = red[0][r][cl] + red[1][r][cl] + red[2][r][cl] + red[3][r][cl];
    g[(ri0 + r) * S + j0 + cl] = s;
    gT[(b * S + j0 + cl) * S + ((ri0 + r) & 255)] = s;
}

// ---------- K5: softmax row (grid 512, block 256) ----------
__global__ __launch_bounds__(256) void k_soft(
    const float* __restrict__ g, const float* __restrict__ gT,
    const float* __restrict__ mask, const float* __restrict__ b2p,
    float* __restrict__ attn)
{
    __shared__ float redm[4], reds[4];
    int i = blockIdx.x;          // global row (batch folded)
    int b = i >> 8;
    int t = threadIdx.x;
    float sv = g[i * S + t] + gT[i * S + t] + 2.0f * b2p[0] + mask[b * S + t] * (-1e9f);
    float wm = wave_max(sv);
    if (!(t & 63)) redm[t >> 6] = wm;
    __syncthreads();
    float m = fmaxf(fmaxf(redm[0], redm[1]), fmaxf(redm[2], redm[3]));
    float e = __expf(sv - m);
    float ws = wave_sum(e);
    if (!(t & 63)) reds[t >> 6] = ws;
    __syncthreads();
    float inv = 1.0f / (reds[0] + reds[1] + reds[2] + reds[3]);
    attn[i * S + t] = e * inv;
}

// ---------- K6: ao = attn @ qkv  (row-block GEMM, grid (128,4), block 256) ----------
__global__ __launch_bounds__(256) void k_av(
    const float* __restrict__ attn, const float* __restrict__ qkv,
    float* __restrict__ ao)
{
    __shared__ float red[4][4][64];
    int r0 = blockIdx.x * 4, c0 = blockIdx.y * 64;
    int b = r0 >> 8;
    const float* W = qkv + b * (S * D);
    int kq = threadIdx.x >> 6, cl = threadIdx.x & 63;
    int c = c0 + cl, k0 = kq * 64;
    float a0 = 0.f, a1 = 0.f, a2 = 0.f, a3 = 0.f;
#pragma unroll 4
    for (int kk = 0; kk < 64; kk += 4) {
        int k = k0 + kk;
        float4 h0 = *(const float4*)&attn[(r0 + 0) * S + k];
        float4 h1 = *(const float4*)&attn[(r0 + 1) * S + k];
        float4 h2 = *(const float4*)&attn[(r0 + 2) * S + k];
        float4 h3 = *(const float4*)&attn[(r0 + 3) * S + k];
        float w0 = W[(k + 0) * D + c], w1 = W[(k + 1) * D + c];
        float w2 = W[(k + 2) * D + c], w3 = W[(k + 3) * D + c];
        a0 = fmaf(h0.x, w0, a0); a0 = fmaf(h0.y, w1, a0); a0 = fmaf(h0.z, w2, a0); a0 = fmaf(h0.w, w3, a0);
        a1 = fmaf(h1.x, w0, a1); a1 = fmaf(h1.y, w1, a1); a1 = fmaf(h1.z, w2, a1); a1 = fmaf(h1.w, w3, a1);
        a2 = fmaf(h2.x, w0, a2); a2 = fmaf(h2.y, w1, a2); a2 = fmaf(h2.z, w2, a2); a2 = fmaf(h2.w, w3, a2);
        a3 = fmaf(h3.x, w0, a3); a3 = fmaf(h3.y, w1, a3); a3 = fmaf(h3.z, w2, a3); a3 = fmaf(h3.w, w3, a3);
    }
    red[kq][0][cl] = a0; red[kq][1][cl] = a1; red[kq][2][cl] = a2; red[kq][3][cl] = a3;
    __syncthreads();
    int r = threadIdx.x >> 6;
    float s = red[0][r][cl] + red[1][r][cl] + red[2][r][cl] + red[3][r][cl];
    ao[(r0 + r) * D + c] = s;
}

// ---------- K7: o1 = LN1(h + ao@outW + outb)  (grid 128, block 1024) ----------
// 1024 thr = 4 kq-groups x 256 cols; 4 rows per block
__global__ __launch_bounds__(1024) void k_proj_ln(
    const float* __restrict__ ao, const float* __restrict__ outW, const float* __restrict__ outb,
    const float* __restrict__ h, const float* __restrict__ lng, const float* __restrict__ lnb,
    float* __restrict__ o1)
{
    __shared__ float red[4][4][256];
    __shared__ float redw[16];
    int r0 = blockIdx.x * 4;
    int t = threadIdx.x;
    int kq = t >> 8, c = t & 255;
    int k0 = kq * 64;
    float a0 = 0.f, a1 = 0.f, a2 = 0.f, a3 = 0.f;
#pragma unroll 4
    for (int kk = 0; kk < 64; kk += 4) {
        int k = k0 + kk;
        float4 h0 = *(const float4*)&ao[(r0 + 0) * D + k];
        float4 h1 = *(const float4*)&ao[(r0 + 1) * D + k];
        float4 h2 = *(const float4*)&ao[(r0 + 2) * D + k];
        float4 h3 = *(const float4*)&ao[(r0 + 3) * D + k];
        float w0 = outW[(k + 0) * D + c], w1 = outW[(k + 1) * D + c];
        float w2 = outW[(k + 2) * D + c], w3 = outW[(k + 3) * D + c];
        a0 = fmaf(h0.x, w0, a0); a0 = fmaf(h0.y, w1, a0); a0 = fmaf(h0.z, w2, a0); a0 = fmaf(h0.w, w3, a0);
        a1 = fmaf(h1.x, w0, a1); a1 = fmaf(h1.y, w1, a1); a1 = fmaf(h1.z, w2, a1); a1 = fmaf(h1.w, w3, a1);
        a2 = fmaf(h2.x, w0, a2); a2 = fmaf(h2.y, w1, a2); a2 = fmaf(h2.z, w2, a2); a2 = fmaf(h2.w, w3, a2);
        a3 = fmaf(h3.x, w0, a3); a3 = fmaf(h3.y, w1, a3); a3 = fmaf(h3.z, w2, a3); a3 = fmaf(h3.w, w3, a3);
    }
    red[kq][0][c] = a0; red[kq][1][c] = a1; red[kq][2][c] = a2; red[kq][3][c] = a3;
    __syncthreads();
    int rr = t >> 8;                     // group rr handles row r0+rr
    float s = red[0][rr][c] + red[1][rr][c] + red[2][rr][c] + red[3][rr][c] + outb[c];
    float v = h[(r0 + rr) * D + c] + s;  // RES=1, ALT=1
    float wsum = wave_sum(v);
    if (!(t & 63)) redw[t >> 6] = wsum;
    __syncthreads();
    float mu = (redw[rr * 4] + redw[rr * 4 + 1] + redw[rr * 4 + 2] + redw[rr * 4 + 3]) * (1.0f / 256.0f);
    float dv = v - mu;
    float w2s = wave_sum(dv * dv);
    __syncthreads();
    if (!(t & 63)) redw[t >> 6] = w2s;
    __syncthreads();
    float var = (redw[rr * 4] + redw[rr * 4 + 1] + redw[rr * 4 + 2] + redw[rr * 4 + 3]) * (1.0f / 256.0f);
    o1[(r0 + rr) * D + c] = dv * rsqrtf(var + 1e-6f) * lng[c] + lnb[c];
}

// ---------- K8: f1 = relu(o1 @ ffnW1 + b1)  (grid (64,16), block 256, Br=8) ----------
__global__ __launch_bounds__(256) void k_ffn1(
    const float* __restrict__ o1, const float* __restrict__ W1, const float* __restrict__ b1,
    float* __restrict__ f1)
{
    __shared__ float red[4][8][64];
    int r0 = blockIdx.x * 8, c0 = blockIdx.y * 64;
    int kq = threadIdx.x >> 6, cl = threadIdx.x & 63;
    int c = c0 + cl, k0 = kq * 64;
    float acc[8];
#pragma unroll
    for (int r = 0; r < 8; r++) acc[r] = 0.f;
#pragma unroll 2
    for (int kk = 0; kk < 64; kk += 4) {
        int k = k0 + kk;
        float w0 = W1[(k + 0) * DFF + c], w1 = W1[(k + 1) * DFF + c];
        float w2 = W1[(k + 2) * DFF + c], w3 = W1[(k + 3) * DFF + c];
#pragma unroll
        for (int r = 0; r < 8; r++) {
            float4 hv = *(const float4*)&o1[(r0 + r) * D + k];
            acc[r] = fmaf(hv.x, w0, acc[r]); acc[r] = fmaf(hv.y, w1, acc[r]);
            acc[r] = fmaf(hv.z, w2, acc[r]); acc[r] = fmaf(hv.w, w3, acc[r]);
        }
    }
#pragma unroll
    for (int r = 0; r < 8; r++) red[kq][r][cl] = acc[r];
    __syncthreads();
    float bv = b1[c];
#pragma unroll
    for (int p = 0; p < 2; p++) {
        int r = (threadIdx.x >> 6) + p * 4;
        float s = red[0][r][cl] + red[1][r][cl] + red[2][r][cl] + red[3][r][cl];
        f1[(r0 + r) * DFF + c] = fmaxf(s + bv, 0.f);
    }
}

// ---------- K9: h' = LN2(o1 + f1@ffnW2 + b2)  (grid 128, block 1024, K=1024) ----------
__global__ __launch_bounds__(1024) void k_ffn2_ln(
    const float* __restrict__ f1, const float* __restrict__ W2, const float* __restrict__ b2,
    const float* __restrict__ o1, const float* __restrict__ lng, const float* __restrict__ lnb,
    float* __restrict__ hout)
{
    __shared__ float red[4][4][256];
    __shared__ float redw[16];
    int r0 = blockIdx.x * 4;
    int t = threadIdx.x;
    int kq = t >> 8, c = t & 255;
    int k0 = kq * 256;
    float a0 = 0.f, a1 = 0.f, a2 = 0.f, a3 = 0.f;
#pragma unroll 2
    for (int kk = 0; kk < 256; kk += 4) {
        int k = k0 + kk;
        float4 h0 = *(const float4*)&f1[(r0 + 0) * DFF + k];
        float4 h1 = *(const float4*)&f1[(r0 + 1) * DFF + k];
        float4 h2 = *(const float4*)&f1[(r0 + 2) * DFF + k];
        float4 h3 = *(const float4*)&f1[(r0 + 3) * DFF + k];
        float w0 = W2[(k + 0) * D + c], w1 = W2[(k + 1) * D + c];
        float w2 = W2[(k + 2) * D + c], w3 = W2[(k + 3) * D + c];
        a0 = fmaf(h0.x, w0, a0); a0 = fmaf(h0.y, w1, a0); a0 = fmaf(h0.z, w2, a0); a0 = fmaf(h0.w, w3, a0);
        a1 = fmaf(h1.x, w0, a1); a1 = fmaf(h1.y, w1, a1); a1 = fmaf(h1.z, w2, a1); a1 = fmaf(h1.w, w3, a1);
        a2 = fmaf(h2.x, w0, a2); a2 = fmaf(h2.y, w1, a2); a2 = fmaf(h2.z, w2, a2); a2 = fmaf(h2.w, w3, a2);
        a3 = fmaf(h3.x, w0, a3); a3 = fmaf(h3.y, w1, a3); a3 = fmaf(h3.z, w2, a3); a3 = fmaf(h3.w, w3, a3);
    }
    red[kq][0][c] = a0; red[kq][1][c] = a1; red[kq][2][c] = a2; red[kq][3][c] = a3;
    __syncthreads();
    int rr = t >> 8;
    float s = red[0][rr][c] + red[1][rr][c] + red[2][rr][c] + red[3][rr][c] + b2[c];
    float v = o1[(r0 + rr) * D + c] + s;
    float wsum = wave_sum(v);
    if (!(t & 63)) redw[t >> 6] = wsum;
    __syncthreads();
    float mu = (redw[rr * 4] + redw[rr * 4 + 1] + redw[rr * 4 + 2] + redw[rr * 4 + 3]) * (1.0f / 256.0f);
    float dv = v - mu;
    float w2s = wave_sum(dv * dv);
    __syncthreads();
    if (!(t & 63)) redw[t >> 6] = w2s;
    __syncthreads();
    float var = (redw[rr * 4] + redw[rr * 4 + 1] + redw[rr * 4 + 2] + redw[rr * 4 + 3]) * (1.0f / 256.0f);
    hout[(r0 + rr) * D + c] = dv * rsqrtf(var + 1e-6f) * lng[c] + lnb[c];
}

extern "C" void kernel_launch(void* const* d_in, const int* in_sizes, int n_in,
                              void* d_out, int out_size, void* d_ws, size_t ws_size,
                              hipStream_t stream)
{
    const int*   x       = (const int*)d_in[0];
    const float* mask    = (const float*)d_in[1];
    const int*   use_pos = (const int*)d_in[3];
    const float* pos_enc = (const float*)d_in[4];
    const float* emb_W   = (const float*)d_in[5];
    const float* emb_b   = (const float*)d_in[6];
    const float* nn_W1   = (const float*)d_in[7];
    const float* nn_b1   = (const float*)d_in[8];
    const float* nn_W2   = (const float*)d_in[9];
    const float* nn_b2   = (const float*)d_in[10];
    const float* w_W     = (const float*)d_in[11];
    const float* w_b     = (const float*)d_in[12];
    const float* out_W   = (const float*)d_in[13];
    const float* out_b   = (const float*)d_in[14];
    const float* ffn_W1  = (const float*)d_in[15];
    const float* ffn_b1  = (const float*)d_in[16];
    const float* ffn_W2  = (const float*)d_in[17];
    const float* ffn_b2  = (const float*)d_in[18];
    const float* ln1_g   = (const float*)d_in[19];
    const float* ln1_b   = (const float*)d_in[20];
    const float* ln2_g   = (const float*)d_in[21];
    const float* ln2_b   = (const float*)d_in[22];

    float* ws   = (float*)d_ws;
    float* h    = ws;                 // 131072
    float* qkv  = ws + 131072;
    float* qa   = ws + 262144;
    float* qbT  = ws + 393216;
    float* g    = ws + 524288;
    float* gT   = ws + 655360;
    float* attn = ws + 786432;
    float* ao   = ws + 917504;
    float* o1   = ws + 1048576;
    float* f1   = ws + 1179648;       // 524288

    k_embed<<<512, 256, 0, stream>>>(x, mask, use_pos, pos_enc, emb_W, emb_b, h);

    for (int l = 0; l < 2; l++) {
        k_qkv<<<dim3(128, 4), 256, 0, stream>>>(h, w_W + l * D * D, w_b + l * D, qkv);
        k_qab<<<dim3(128, 8), 256, 0, stream>>>(qkv, nn_W1, nn_b1, qa, qbT);
        k_g<<<dim3(128, 4), 256, 0, stream>>>(qa, qbT, nn_W2, g, gT);
        k_soft<<<512, 256, 0, stream>>>(g, gT, mask, nn_b2, attn);
        k_av<<<dim3(128, 4), 256, 0, stream>>>(attn, qkv, ao);
        k_proj_ln<<<128, 1024, 0, stream>>>(ao, out_W + l * D * D, out_b + l * D,
                                            h, ln1_g + l * D, ln1_b + l * D, o1);
        k_ffn1<<<dim3(64, 16), 256, 0, stream>>>(o1, ffn_W1 + l * D * DFF,
                                                 ffn_b1 + l * DFF, f1);
        float* hout = (l == 1) ? (float*)d_out : h;
        k_ffn2_ln<<<128, 1024, 0, stream>>>(f1, ffn_W2 + l * DFF * D, ffn_b2 + l * D,
                                            o1, ln2_g + l * D, ln2_b + l * D, hout);
    }
}